// Round 5
// baseline (19.700 us; speedup 1.0000x reference)
//
#include <hip/hip_runtime.h>

// HiddenMerger: the masked softmax's diagonal is exactly 0 for rows m>=1
// (diagonal masked with -2^32; exp underflows in fp32) and exactly 1/L for
// row 0 (every entry of row 0 rounds to exactly -2^32 -> uniform softmax).
//   out[b,0,d]    = (1/L) * sum_l hidden[b,l,d]
//   out[b,m>=1,d] = 0
// Single dispatch, 256 blocks x 1024 threads (1 block/CU, 4 waves/SIMD).
// Block (c,b) owns a 4-float4 (64 B) column slice of batch b:
//   - sums it over all L rows (8 fully-unrolled iters, 8 KB in flight/wave)
//   - zeroes its own 32 output rows (coalesced float4 stores)
//   - LDS tree-reduce 256 ways -> writes its 64 B of row 0 scaled by 1/L
// Every CU: 128 KB read + 128 KB write (copy-shaped). Deterministic order.

namespace {
constexpr int B = 4;
constexpr int L = 2048;
constexpr int D = 1024;
constexpr int D4 = D / 4;          // 256 float4 per row
constexpr int CI = 4;              // float4 columns per block slice (64 B)
constexpr int CHUNKS = D4 / CI;    // 64 column slices per batch
constexpr int NBLK = CHUNKS * B;   // 256 blocks
constexpr int NT = 1024;           // threads per block
constexpr int WAYS = NT / CI;      // 256 row-ways
constexpr int ITERS = L / WAYS;    // 8 read iterations per thread
constexpr int ZROWS = L / CHUNKS;  // 32 rows zeroed per block
}

__global__ __launch_bounds__(NT) void k_fused(const float* __restrict__ hidden,
                                              float* __restrict__ out) {
    const int bid = blockIdx.x;
    const int t = threadIdx.x;
    const int c = bid & (CHUNKS - 1);   // column slice 0..63
    const int b = bid >> 6;             // batch 0..3
    const int ci = t & (CI - 1);        // float4 column within slice
    const int ri = t >> 2;              // row-way 0..255
    const int colf4 = c * CI + ci;      // 0..255

    const float4* hp = reinterpret_cast<const float4*>(hidden + (size_t)b * L * D);
    float4* op = reinterpret_cast<float4*>(out + (size_t)b * L * D);

    // Phase 1: column sum, all loads in flight (full unroll).
    float4 s = make_float4(0.f, 0.f, 0.f, 0.f);
#pragma unroll
    for (int i = 0; i < ITERS; ++i) {
        float4 v = hp[(size_t)(ri + i * WAYS) * D4 + colf4];
        s.x += v.x; s.y += v.y; s.z += v.z; s.w += v.w;
    }

    // Phase 2: zero this block's 32 output rows (4 rows / iteration).
    const int r0 = c * ZROWS;
    const int zro = t >> 8;             // row offset 0..3
    const int zcol = t & (D4 - 1);      // f4 column 0..255
    const float4 zero = make_float4(0.f, 0.f, 0.f, 0.f);
#pragma unroll
    for (int i = 0; i < ZROWS / 4; ++i) {
        const int row = r0 + i * 4 + zro;
        if (row > 0)                    // row 0 gets the sum instead
            op[(size_t)row * D4 + zcol] = zero;
    }

    // Phase 3: LDS tree-reduce 256 row-ways -> 4 float4, write row-0 slice.
    __shared__ float4 red[NT];
    red[t] = s;
    __syncthreads();
    for (int sz = NT / 2; sz >= CI; sz >>= 1) {   // 8 folds, fixed order
        if (t < sz) {
            float4 o = red[t + sz];
            float4 m = red[t];
            m.x += o.x; m.y += o.y; m.z += o.z; m.w += o.w;
            red[t] = m;
        }
        __syncthreads();
    }
    if (t < CI) {
        float4 m = red[t];
        const float sc = 1.0f / (float)L;         // 2^-11, exact
        m.x *= sc; m.y *= sc; m.z *= sc; m.w *= sc;
        op[c * CI + t] = m;
    }
}

extern "C" void kernel_launch(void* const* d_in, const int* in_sizes, int n_in,
                              void* d_out, int out_size, void* d_ws, size_t ws_size,
                              hipStream_t stream) {
    const float* hidden = (const float*)d_in[0];
    float* out = (float*)d_out;
    hipLaunchKernelGGL(k_fused, dim3(NBLK), dim3(NT), 0, stream, hidden, out);
}

// Round 6
// 14.729 us; speedup vs baseline: 1.3375x; 1.3375x over previous
//
#include <hip/hip_runtime.h>

// HiddenMerger: the masked softmax's diagonal is exactly 0 for rows m>=1
// (diagonal masked with -2^32; exp underflows in fp32) and exactly 1/L for
// row 0 (every entry of row 0 rounds to exactly -2^32 -> uniform softmax).
//   out[b,0,d]    = (1/L) * sum_l hidden[b,l,d]
//   out[b,m>=1,d] = 0
// Single dispatch, 256 blocks x 512 threads (8 waves/CU), roles interleaved
// by bid&1 so every XCD carries a balanced read/write mix:
//   even bid (128 blocks): sum block owns an 8-float4 (128 B = full cache
//     line) column slice of one batch; sums it over all L rows with 64
//     row-ways x unroll 16 (~16 float4 in flight per lane), LDS-reduces,
//     writes its 128 B of row 0 scaled by 1/L.
//   odd bid (128 blocks): zero block, grid-strides over 4096 adjacent
//     row-pairs, storing 8 KB contiguous zeros per iteration (row 0 skipped).
// Traffic: 33.5 MB read + 33.5 MB write, every line touched exactly once.

namespace {
constexpr int B = 4;
constexpr int L = 2048;
constexpr int D = 1024;
constexpr int D4 = D / 4;           // 256 float4 per row
constexpr int NT = 512;             // threads per block
constexpr int CI = 8;               // float4 columns per sum slice (128 B)
constexpr int CHUNKS = D4 / CI;     // 32 column slices per batch
constexpr int WAYS = NT / CI;       // 64 row-ways per sum block
constexpr int NSUM = CHUNKS * B;    // 128 sum blocks
constexpr int NZB = 128;            // zero blocks
constexpr int NPAIR = B * L / 2;    // 4096 flat row-pairs
}

__global__ __launch_bounds__(NT) void k_fused(const float* __restrict__ hidden,
                                              float* __restrict__ out) {
    const int bid = blockIdx.x;
    const int t = threadIdx.x;

    if ((bid & 1) == 0) {
        // ---- sum role ----
        const int sidx = bid >> 1;          // 0..127
        const int c = sidx & (CHUNKS - 1);  // column slice 0..31
        const int b = sidx >> 5;            // batch 0..3
        const int ci = t & (CI - 1);        // float4 column within slice
        const int ri = t >> 3;              // row-way 0..63
        const int colf4 = c * CI + ci;      // 0..255

        const float4* hp = reinterpret_cast<const float4*>(hidden + (size_t)b * L * D);
        float4 s = make_float4(0.f, 0.f, 0.f, 0.f);
#pragma unroll 16
        for (int r = ri; r < L; r += WAYS) {            // 32 iterations
            float4 v = hp[(size_t)r * D4 + colf4];
            s.x += v.x; s.y += v.y; s.z += v.z; s.w += v.w;
        }

        __shared__ float4 red[NT];
        red[t] = s;
        __syncthreads();
#pragma unroll
        for (int sh = WAYS / 2; sh > 0; sh >>= 1) {     // 64 -> 1, fixed order
            if (ri < sh) {
                float4 o = red[(ri + sh) * CI + ci];
                float4 m = red[t];
                m.x += o.x; m.y += o.y; m.z += o.z; m.w += o.w;
                red[t] = m;
            }
            __syncthreads();
        }
        if (ri == 0) {
            float4 m = red[ci];
            const float sc = 1.0f / (float)L;           // 2^-11, exact
            m.x *= sc; m.y *= sc; m.z *= sc; m.w *= sc;
            reinterpret_cast<float4*>(out + (size_t)b * L * D)[colf4] = m;
        }
    } else {
        // ---- zero role: grid-stride over adjacent flat row-pairs ----
        const int zidx = bid >> 1;          // 0..127
        const int rp = t >> 8;              // 0..1: which row of the pair
        const int col = t & (D4 - 1);       // f4 column 0..255
        const float4 zero = make_float4(0.f, 0.f, 0.f, 0.f);
        for (int p = zidx; p < NPAIR; p += NZB) {       // 32 iterations
            const int fr = 2 * p + rp;      // flat row 0..8191
            const int row = fr & (L - 1);
            if (row > 0)                    // batch row 0 gets the sum instead
                reinterpret_cast<float4*>(out)[(size_t)fr * D4 + col] = zero;
        }
    }
}

extern "C" void kernel_launch(void* const* d_in, const int* in_sizes, int n_in,
                              void* d_out, int out_size, void* d_ws, size_t ws_size,
                              hipStream_t stream) {
    const float* hidden = (const float*)d_in[0];
    float* out = (float*)d_out;
    hipLaunchKernelGGL(k_fused, dim3(NSUM + NZB), dim3(NT), 0, stream, hidden, out);
}